// Round 11
// baseline (299.604 us; speedup 1.0000x reference)
//
#include <hip/hip_runtime.h>
#include <stdint.h>

#define T_SEQ 2048
#define NH 16
#define HD 64
#define DM 1024
#define BB 4
#define MROWS (BB * T_SEQ)   // 8192

// Q projection is pre-scaled by 1/sqrt(HD) * log2(e) so attention scores are
// already in the log2 domain: P = exp2(s - m), alpha = exp2(m_old - m_new).
#define QSCALE 0.18033688011112042f  // 0.125 * log2(e)

typedef __attribute__((ext_vector_type(8))) __bf16 bf16x8;
typedef __attribute__((ext_vector_type(8))) unsigned short u16x8;
typedef __attribute__((ext_vector_type(4))) unsigned short u16x4;
typedef __attribute__((ext_vector_type(4))) float f32x4;

// Native cast -> compiler emits v_cvt_pk_bf16_f32 (RNE, pairs fuse).
__device__ __forceinline__ unsigned short f2bf(float f) {
  return __builtin_bit_cast(unsigned short, (__bf16)f);
}

__device__ __forceinline__ bf16x8 ld8_f32(const float* __restrict__ p) {
  f32x4 a = *(const f32x4*)p;
  f32x4 b = *(const f32x4*)(p + 4);
  u16x8 u;
#pragma unroll
  for (int i = 0; i < 4; ++i) {
    u[i]     = f2bf(a[i]);
    u[i + 4] = f2bf(b[i]);
  }
  return __builtin_bit_cast(bf16x8, u);
}

__device__ __forceinline__ bf16x8 ld8_bf(const unsigned short* p) {
  return __builtin_bit_cast(bf16x8, *(const u16x8*)p);
}

// 8-aligned LDS read as two b64s (stride-68 layouts are not 16B-aligned)
__device__ __forceinline__ bf16x8 ld8_lds(const unsigned short* p) {
  u16x4 a = *(const u16x4*)p;
  u16x4 b = *(const u16x4*)(p + 4);
  return __builtin_bit_cast(bf16x8,
      __builtin_shufflevector(a, b, 0, 1, 2, 3, 4, 5, 6, 7));
}

__device__ __forceinline__ u16x4 lo4(u16x8 v) {
  return __builtin_shufflevector(v, v, 0, 1, 2, 3);
}
__device__ __forceinline__ u16x4 hi4(u16x8 v) {
  return __builtin_shufflevector(v, v, 4, 5, 6, 7);
}

__device__ __forceinline__ void gload_lds16(const unsigned short* g,
                                            unsigned short* l) {
  __builtin_amdgcn_global_load_lds(
      (const __attribute__((address_space(1))) unsigned int*)g,
      (__attribute__((address_space(3))) unsigned int*)l, 16, 0, 0);
}

// ---------------------------------------------------------------------------
// Fused stage-1 conversion — 4 weights + x_kv + x_q in ONE dispatch.
// ---------------------------------------------------------------------------
__global__ __launch_bounds__(256) void conv_stage1(
    const float* __restrict__ Wk, const float* __restrict__ Wv,
    const float* __restrict__ Wq, const float* __restrict__ Wo,
    const float* __restrict__ xkv, const float* __restrict__ xq,
    unsigned short* __restrict__ Wkb012, unsigned short* __restrict__ Wob,
    unsigned short* __restrict__ Sxkv, unsigned short* __restrict__ Sxq) {
  const int bid = blockIdx.x;
  const int WSEG = (DM * DM / 8) / 256;   // 512 blocks per weight
  const int XSEG = (MROWS * DM / 8) / 256;  // 4096 blocks per activation
  if (bid < 4 * WSEG) {
    const int w = bid >> 9;
    const float* src = (w == 0) ? Wk : (w == 1) ? Wv : (w == 2) ? Wq : Wo;
    unsigned short* dst = (w < 3) ? Wkb012 + (size_t)w * DM * DM : Wob;
    const int i = (bid & (WSEG - 1)) * 256 + threadIdx.x;
    *(u16x8*)(dst + (size_t)i * 8) =
        __builtin_bit_cast(u16x8, ld8_f32(src + (size_t)i * 8));
  } else if (bid < 4 * WSEG + XSEG) {
    const int i = (bid - 4 * WSEG) * 256 + threadIdx.x;
    *(u16x8*)(Sxkv + (size_t)i * 8) =
        __builtin_bit_cast(u16x8, ld8_f32(xkv + (size_t)i * 8));
  } else {
    const int i = (bid - 4 * WSEG - XSEG) * 256 + threadIdx.x;
    *(u16x8*)(Sxq + (size_t)i * 8) =
        __builtin_bit_cast(u16x8, ld8_f32(xq + (size_t)i * 8));
  }
}

// ---------------------------------------------------------------------------
// R11: QKV mega-GEMM with COUNTED-VMCNT 4-PHASE schedule (T3+T4+T2+T5).
// C = A[M,K] @ B[N,K]^T, BM=BN=256, BK=64, 512 thr (8 waves, 2M x 4N;
// per-wave out 128x64, acc[8][4]). 2 K-tile LDS buffers (128 KB).
//
// Pipeline (derived, hazard-checked):
//   prologue: stage tile0->buf0, tile1->buf1 (8 gload_lds each); vmcnt(8)
//     (tile0 landed, tile1 in flight); barrier.
//   iter kt (buf cur=kt&1): 4 phases x {A-frag ds_reads, setprio(1),
//     16 MFMA, setprio(0), raw s_barrier}; B-frags read once, live all tile.
//   boundary: lgkmcnt(0)+barrier (all reads of buf cur retired) -> issue
//     tile kt+2 -> buf cur (8 loads) -> vmcnt(8) (= tile kt+1's loads, which
//     flew for one FULL iter ~620cy > HBM latency, landed; kt+2's 8 remain
//     outstanding) -> barrier. Never drains to 0 in steady state (T4).
// LDS slot-swizzle (T2, rule #21 both-sides): physical 16B-slot =
//   logical ^ (row&7), applied at the GLOBAL source col (linear gload_lds
//   dest then lands swizzled) and at ds_read. Kills the 16-way ds_read_b128
//   conflict of linear [128][64] (fr-lanes all in one bank group -> 2/bank).
// Epilogue three-way: n<1024 K row-major; n<2048 Vt[b][h][d][t]; else Q
//   row-major * QSCALE. All branches block-uniform (n0 multiple of 256).
// ---------------------------------------------------------------------------
__global__ __launch_bounds__(512, 2) void gemm_qkv_p4(
    const unsigned short* __restrict__ Axkv,
    const unsigned short* __restrict__ Axq,
    const unsigned short* __restrict__ B, unsigned short* __restrict__ Ck,
    unsigned short* __restrict__ Cvt, unsigned short* __restrict__ Cq,
    int M, int N, int K) {
  __shared__ __align__(16) unsigned short As[2][2][128 * 64];
  __shared__ __align__(16) unsigned short Bs[2][2][128 * 64];

  const int t = threadIdx.x;               // 0..511
  const int lane = t & 63, wave = t >> 6;  // 8 waves
  const int lin = (int)(blockIdx.x + gridDim.x * blockIdx.y);  // 0..383
  const int nx = N >> 8;                   // 12
  const int mpx = (M >> 8) >> 3;           // 4 m-panels per XCD
  const int xcd = lin & 7, slot = lin >> 3;
  const int m0 = (xcd * mpx + slot / nx) * 256;
  const int n0 = (slot % nx) * 256;

  const unsigned short* A = (n0 >= 2 * DM) ? Axq : Axkv;  // block-uniform

  // staging: one gload_lds call = 512 thr x 16B = 64 rows x 64 cols bf16.
  // thread t -> row tr, swizzled source col tc (so linear LDS dest ends up
  // slot-swizzled: physical slot (t&7) holds logical slot (t&7)^(tr&7)).
  const int tr = t >> 3;                        // 0..63
  const int tc = ((t & 7) ^ (tr & 7)) * 8;      // u16
  const unsigned short* ga = A + (size_t)(m0 + tr) * K + tc;
  const unsigned short* gb = B + (size_t)(n0 + tr) * K + tc;
  const int ldst = wave * 512;                  // u16; + c*4096 per call

  const int wm = wave >> 2, wn = wave & 3;      // 2M x 4N wave grid
  const int fr = lane & 15, quad = lane >> 4;
  const int sw = fr & 7;                        // row&7 for all frag rows

  f32x4 acc[8][4];
#pragma unroll
  for (int i = 0; i < 8; ++i)
#pragma unroll
    for (int j = 0; j < 4; ++j) acc[i][j] = (f32x4){0.f, 0.f, 0.f, 0.f};

  auto stage_tile = [&](int b, int k0) {  // 8 gload_lds per thread
#pragma unroll
    for (int h = 0; h < 2; ++h)
#pragma unroll
      for (int c = 0; c < 2; ++c) {
        gload_lds16(ga + (size_t)(h * 128 + c * 64) * K + k0,
                    &As[b][h][c * 4096 + ldst]);
        gload_lds16(gb + (size_t)(h * 128 + c * 64) * K + k0,
                    &Bs[b][h][c * 4096 + ldst]);
      }
  };

  stage_tile(0, 0);
  stage_tile(1, 64);
  asm volatile("s_waitcnt vmcnt(8)" ::: "memory");  // tile0 landed
  __builtin_amdgcn_s_barrier();

  const int NT = K >> 6;  // 16
  for (int kt = 0; kt < NT; ++kt) {
    const int cur = kt & 1;
    // B-frags for the whole K-tile (8 x ds_read_b128), live across phases.
    bf16x8 bfr[2][4];
#pragma unroll
    for (int ks = 0; ks < 2; ++ks)
#pragma unroll
      for (int j = 0; j < 4; ++j) {
        const int br = (wn & 1) * 64 + j * 16 + fr;  // br&7 == fr&7
        bfr[ks][j] =
            ld8_bf(&Bs[cur][wn >> 1][br * 64 + ((ks * 4 + quad) ^ sw) * 8]);
      }
#pragma unroll
    for (int p = 0; p < 4; ++p) {
      bf16x8 af[2][2];  // [di][ks]
#pragma unroll
      for (int di = 0; di < 2; ++di)
#pragma unroll
        for (int ks = 0; ks < 2; ++ks) {
          const int ar = (p * 2 + di) * 16 + fr;     // ar&7 == fr&7
          af[di][ks] =
              ld8_bf(&As[cur][wm][ar * 64 + ((ks * 4 + quad) ^ sw) * 8]);
        }
      __builtin_amdgcn_s_setprio(1);
#pragma unroll
      for (int di = 0; di < 2; ++di)
#pragma unroll
        for (int j = 0; j < 4; ++j)
#pragma unroll
          for (int ks = 0; ks < 2; ++ks)
            acc[p * 2 + di][j] = __builtin_amdgcn_mfma_f32_16x16x32_bf16(
                af[di][ks], bfr[ks][j], acc[p * 2 + di][j], 0, 0, 0);
      __builtin_amdgcn_s_setprio(0);
      if (p < 3) __builtin_amdgcn_s_barrier();  // raw: phase alignment only
    }
    // ---- K-tile boundary ----
    asm volatile("s_waitcnt lgkmcnt(0)" ::: "memory");  // my reads retired
    __builtin_amdgcn_s_barrier();   // all waves done reading buf cur
    if (kt + 2 < NT) {
      stage_tile(cur, (kt + 2) << 6);                   // overwrite buf cur
      asm volatile("s_waitcnt vmcnt(8)" ::: "memory");  // tile kt+1 landed
    } else {
      asm volatile("s_waitcnt vmcnt(0)" ::: "memory");  // tail drain
    }
    __builtin_amdgcn_s_barrier();   // tile kt+1 visible to all waves
  }

  // ---- epilogue: three-way QKV scatter ----
  const int orow = (lane >> 4) * 4, ocol = lane & 15;
  const int mwo = wm * 128, nwo = wn * 64;
#pragma unroll
  for (int i = 0; i < 8; ++i)
#pragma unroll
    for (int j = 0; j < 4; ++j) {
      const int mb = m0 + mwo + i * 16 + orow;
      const int n = n0 + nwo + j * 16 + ocol;
      if (n0 < DM) {            // K: bf16 row-major, stride DM
#pragma unroll
        for (int r = 0; r < 4; ++r)
          Ck[(size_t)(mb + r) * DM + n] = f2bf(acc[i][j][r]);
      } else if (n0 < 2 * DM) {  // V: Vt[b][h][d][t], 4 r = consecutive t
        const int nv = n - DM;
        u16x4 pk;
#pragma unroll
        for (int r = 0; r < 4; ++r) pk[r] = f2bf(acc[i][j][r]);
        unsigned short* dst = Cvt +
            ((size_t)((mb >> 11) * NH + (nv >> 6)) * HD + (nv & 63)) * T_SEQ +
            (mb & 2047);
        *(u16x4*)dst = pk;
      } else {                  // Q: bf16 row-major * QSCALE
        const int nq = n - 2 * DM;
#pragma unroll
        for (int r = 0; r < 4; ++r)
          Cq[(size_t)(mb + r) * DM + nq] = f2bf(acc[i][j][r] * QSCALE);
      }
    }
}

// ---------------------------------------------------------------------------
// bf16 GEMM (proven R7 structure) — used for the O projection only.
// 128x128 tile, BK=64, 2-phase dbuf gload_lds staging, XCD remap.
// MODE 1: f32 row-major out.
// ---------------------------------------------------------------------------
template <int MODE>
__global__ __launch_bounds__(256) void gemm128(
    const unsigned short* __restrict__ A, const unsigned short* __restrict__ B,
    void* __restrict__ Cv, int M, int N, int K) {
  __shared__ __align__(16) unsigned short As[2][2][128 * 32];
  __shared__ __align__(16) unsigned short Bs[2][2][128 * 32];

  const int t = threadIdx.x;
  const int lane = t & 63, wave = t >> 6;
  const int lin = (int)(blockIdx.x + gridDim.x * blockIdx.y);
  const int nx = N >> 7;
  const int mpx = (M >> 7) >> 3;
  const int xcd = lin & 7, slot = lin >> 3;
  const int m0 = (xcd * mpx + slot / nx) * 128;
  const int n0 = (slot % nx) * 128;

  const int srow = t >> 2;
  const int scol = (t & 3) * 8;
  const unsigned short* ga0 = A + (size_t)(m0 + srow) * K + scol;
  const unsigned short* ga1 = A + (size_t)(m0 + 64 + srow) * K + scol;
  const unsigned short* gb0 = B + (size_t)(n0 + srow) * K + scol;
  const unsigned short* gb1 = B + (size_t)(n0 + 64 + srow) * K + scol;
  const int lo0 = (wave * 16) * 32, lo1 = (64 + wave * 16) * 32;

  const int mw = (wave >> 1) * 64, nw = (wave & 1) * 64;
  const int fr = lane & 15, fq = (lane >> 4) * 8;

  f32x4 acc[4][4];
#pragma unroll
  for (int i = 0; i < 4; ++i)
#pragma unroll
    for (int j = 0; j < 4; ++j) acc[i][j] = (f32x4){0.f, 0.f, 0.f, 0.f};

  auto stage = [&](int buf, int k0) {
    gload_lds16(ga0 + k0,      &As[buf][0][lo0]);
    gload_lds16(ga1 + k0,      &As[buf][0][lo1]);
    gload_lds16(gb0 + k0,      &Bs[buf][0][lo0]);
    gload_lds16(gb1 + k0,      &Bs[buf][0][lo1]);
    gload_lds16(ga0 + k0 + 32, &As[buf][1][lo0]);
    gload_lds16(ga1 + k0 + 32, &As[buf][1][lo1]);
    gload_lds16(gb0 + k0 + 32, &Bs[buf][1][lo0]);
    gload_lds16(gb1 + k0 + 32, &Bs[buf][1][lo1]);
  };

  stage(0, 0);
  __syncthreads();

  const int NT = K >> 6;
  int cur = 0;
  for (int kt = 0; kt < NT; ++kt) {
    if (kt + 1 < NT) stage(cur ^ 1, (kt + 1) << 6);
#pragma unroll
    for (int ks = 0; ks < 2; ++ks) {
      bf16x8 af[4], bfr[4];
#pragma unroll
      for (int i = 0; i < 4; ++i)
        af[i] = ld8_bf(&As[cur][ks][(mw + i * 16 + fr) * 32 + fq]);
#pragma unroll
      for (int j = 0; j < 4; ++j)
        bfr[j] = ld8_bf(&Bs[cur][ks][(nw + j * 16 + fr) * 32 + fq]);
#pragma unroll
      for (int i = 0; i < 4; ++i)
#pragma unroll
        for (int j = 0; j < 4; ++j)
          acc[i][j] = __builtin_amdgcn_mfma_f32_16x16x32_bf16(
              af[i], bfr[j], acc[i][j], 0, 0, 0);
    }
    __syncthreads();
    cur ^= 1;
  }

  const int orow = (lane >> 4) * 4, ocol = lane & 15;
#pragma unroll
  for (int i = 0; i < 4; ++i)
#pragma unroll
    for (int j = 0; j < 4; ++j) {
      const int mb = m0 + mw + i * 16 + orow;
      const int n = n0 + nw + j * 16 + ocol;
#pragma unroll
      for (int r = 0; r < 4; ++r)
        ((float*)Cv)[(size_t)(mb + r) * N + n] = acc[i][j][r];
    }
}

// ---------------------------------------------------------------------------
// MFMA flash attention v2 (causal) — R7 version (best measured 88-91 µs).
// Paired q-tiles {15-pi, pi}; S^T = K @ Q^T; scores pre-scaled to log2
// domain; defer-max THR=8; alpha/l via width-16 shuffles; K/V LDS
// double-buffer, 1 barrier/tile.
// ---------------------------------------------------------------------------
#define ASTR 68

__global__ __launch_bounds__(256, 2) void attn_flash2(
    const unsigned short* Qw, const unsigned short* __restrict__ Kw,
    const unsigned short* __restrict__ Vt, unsigned short* Ow) {
  __shared__ __align__(16) unsigned short k_lds[2][64][ASTR];
  __shared__ __align__(16) unsigned short vt_lds[2][64][ASTR];
  __shared__ __align__(16) unsigned short p_lds[4][32][ASTR];

  const int tid = threadIdx.x, lane = tid & 63, wave = tid >> 6;
  const int c16 = lane & 15, quad = lane >> 4;
  const int b = blockIdx.z, h = blockIdx.y;
  const int pi = blockIdx.x;            // pair index 0..7
  const int qb0A = (15 - pi) * 128;     // heavy
  const int qb0B = pi * 128;            // light
  const size_t rkbase = (size_t)b * T_SEQ * DM + (size_t)h * HD;
  const size_t vtbase = (size_t)(b * NH + h) * HD * T_SEQ;

  const int q_loA = qb0A + wave * 32;
  const int q_loB = qb0B + wave * 32;

  bf16x8 qfA[2][2], qfB[2][2];
#pragma unroll
  for (int nf = 0; nf < 2; ++nf) {
    const unsigned short* qpA =
        Qw + rkbase + (size_t)(q_loA + nf * 16 + c16) * DM + quad * 8;
    qfA[nf][0] = ld8_bf(qpA);
    qfA[nf][1] = ld8_bf(qpA + 32);
    const unsigned short* qpB =
        Qw + rkbase + (size_t)(q_loB + nf * 16 + c16) * DM + quad * 8;
    qfB[nf][0] = ld8_bf(qpB);
    qfB[nf][1] = ld8_bf(qpB + 32);
  }

  f32x4 oA[2][4], oB[2][4];
#pragma unroll
  for (int nf = 0; nf < 2; ++nf)
#pragma unroll
    for (int j = 0; j < 4; ++j) {
      oA[nf][j] = (f32x4){0.f, 0.f, 0.f, 0.f};
      oB[nf][j] = (f32x4){0.f, 0.f, 0.f, 0.f};
    }
  float mA[2] = {-3.0e38f, -3.0e38f}, lA[2] = {0.f, 0.f};
  float mB[2] = {-3.0e38f, -3.0e38f}, lB[2] = {0.f, 0.f};

  const int srow = tid >> 2;
  const int scol = (tid & 3) * 16;
  const int ntiles = (qb0A + 191) >> 6;
  const int ntA_w = (q_loA + 95) >> 6;
  const int ntB_w = (q_loB + 95) >> 6;

  const unsigned short* kp0 = Kw + rkbase + (size_t)srow * DM + scol;
  const unsigned short* vp0 = Vt + vtbase + (size_t)srow * T_SEQ + scol;

  auto subtile = [&](const bf16x8 (&qf)[2][2], f32x4 (&o)[2][4],
                     float (&m_r)[2], float (&l_r)[2], const int q_lo,
                     const int kb0, const int bi) {
    f32x4 s[4][2];
    __builtin_amdgcn_s_setprio(1);
#pragma unroll
    for (int mf = 0; mf < 4; ++mf) {
      const unsigned short* kr = &k_lds[bi][mf * 16 + c16][quad * 8];
      const bf16x8 k0 = ld8_lds(kr);
      const bf16x8 k1 = ld8_lds(kr + 32);
#pragma unroll
      for (int nf = 0; nf < 2; ++nf) {
        f32x4 a = {0.f, 0.f, 0.f, 0.f};
        a = __builtin_amdgcn_mfma_f32_16x16x32_bf16(k0, qf[nf][0], a, 0, 0, 0);
        a = __builtin_amdgcn_mfma_f32_16x16x32_bf16(k1, qf[nf][1], a, 0, 0, 0);
        s[mf][nf] = a;
      }
    }
    __builtin_amdgcn_s_setprio(0);
    if (kb0 + 63 > q_lo) {
#pragma unroll
      for (int mf = 0; mf < 4; ++mf) {
        const int key0 = kb0 + mf * 16 + quad * 4;
#pragma unroll
        for (int nf = 0; nf < 2; ++nf) {
          const int qg = q_lo + nf * 16 + c16;
#pragma unroll
          for (int r = 0; r < 4; ++r)
            if (key0 + r > qg) s[mf][nf][r] = -3.0e38f;
        }
      }
    }

#pragma unroll
    for (int nf = 0; nf < 2; ++nf) {
      float mx = -3.0e38f;
#pragma unroll
      for (int mf = 0; mf < 4; ++mf)
#pragma unroll
        for (int r = 0; r < 4; ++r) mx = fmaxf(mx, s[mf][nf][r]);
      mx = fmaxf(mx, __shfl_xor(mx, 16, 64));
      mx = fmaxf(mx, __shfl_xor(mx, 32, 64));
      if (!__all(mx - m_r[nf] <= 8.0f)) {
        const float m_new = fmaxf(m_r[nf], mx);
        const float al = exp2f(m_r[nf] - m_new);
        m_r[nf] = m_new;
        l_r[nf] *= al;
        float alr[4];
#pragma unroll
        for (int r = 0; r < 4; ++r) alr[r] = __shfl(al, quad * 4 + r, 16);
#pragma unroll
        for (int j = 0; j < 4; ++j)
#pragma unroll
          for (int r = 0; r < 4; ++r) o[nf][j][r] *= alr[r];
      }
      float ps = 0.f;
#pragma unroll
      for (int mf = 0; mf < 4; ++mf) {
        u16x4 pk;
#pragma unroll
        for (int r = 0; r < 4; ++r) {
          const float e = exp2f(s[mf][nf][r] - m_r[nf]);
          ps += e;
          pk[r] = f2bf(e);
        }
        *(u16x4*)&p_lds[wave][nf * 16 + c16][mf * 16 + quad * 4] = pk;
      }
      ps += __shfl_xor(ps, 16, 64);
      ps += __shfl_xor(ps, 32, 64);
      l_r[nf] += ps;
    }
    __threadfence_block();

    bf16x8 pf[2][2];
#pragma unroll
    for (int nf = 0; nf < 2; ++nf) {
      const unsigned short* pw = &p_lds[wave][nf * 16 + c16][quad * 8];
      pf[nf][0] = ld8_lds(pw);
      pf[nf][1] = ld8_lds(pw + 32);
    }
    __builtin_amdgcn_s_setprio(1);
#pragma unroll
    for (int j = 0; j < 4; ++j) {
      const unsigned short* vr = &vt_lds[bi][j * 16 + c16][quad * 8];
      const bf16x8 v0 = ld8_lds(vr);
      const bf16x8 v1 = ld8_lds(vr + 32);
#pragma unroll
      for (int nf = 0; nf < 2; ++nf) {
        o[nf][j] = __builtin_amdgcn_mfma_f32_16x16x32_bf16(pf[nf][0], v0,
                                                           o[nf][j], 0, 0, 0);
        o[nf][j] = __builtin_amdgcn_mfma_f32_16x16x32_bf16(pf[nf][1], v1,
                                                           o[nf][j], 0, 0, 0);
      }
    }
    __builtin_amdgcn_s_setprio(0);
  };

  {
    u16x8 ka = *(const u16x8*)kp0;
    u16x8 kc = *(const u16x8*)(kp0 + 8);
    u16x8 va = *(const u16x8*)vp0;
    u16x8 vc = *(const u16x8*)(vp0 + 8);
    *(u16x4*)&k_lds[0][srow][scol]       = lo4(ka);
    *(u16x4*)&k_lds[0][srow][scol + 4]   = hi4(ka);
    *(u16x4*)&k_lds[0][srow][scol + 8]   = lo4(kc);
    *(u16x4*)&k_lds[0][srow][scol + 12]  = hi4(kc);
    *(u16x4*)&vt_lds[0][srow][scol]      = lo4(va);
    *(u16x4*)&vt_lds[0][srow][scol + 4]  = hi4(va);
    *(u16x4*)&vt_lds[0][srow][scol + 8]  = lo4(vc);
    *(u16x4*)&vt_lds[0][srow][scol + 12] = hi4(vc);
  }
  __syncthreads();

  int cur = 0;
  for (int t = 0; t < ntiles; ++t) {
    const int kb0 = t * 64;
    const bool pf = (t + 1 < ntiles);
    u16x8 ka, kc, va, vc;
    if (pf) {
      const unsigned short* kp = kp0 + (size_t)(kb0 + 64) * DM;
      ka = *(const u16x8*)kp;
      kc = *(const u16x8*)(kp + 8);
      const unsigned short* vp = vp0 + (kb0 + 64);
      va = *(const u16x8*)vp;
      vc = *(const u16x8*)(vp + 8);
    }
    if (t < ntA_w) subtile(qfA, oA, mA, lA, q_loA, kb0, cur);
    if (t < ntB_w) subtile(qfB, oB, mB, lB, q_loB, kb0, cur);
    if (pf) {
      const int nb = cur ^ 1;
      *(u16x4*)&k_lds[nb][srow][scol]       = lo4(ka);
      *(u16x4*)&k_lds[nb][srow][scol + 4]   = hi4(ka);
      *(u16x4*)&k_lds[nb][srow][scol + 8]   = lo4(kc);
      *(u16x4*)&k_lds[nb][srow][scol + 12]  = hi4(kc);
      *(u16x4*)&vt_lds[nb][srow][scol]      = lo4(va);
      *(u16x4*)&vt_lds[nb][srow][scol + 4]  = hi4(va);
      *(u16x4*)&vt_lds[nb][srow][scol + 8]  = lo4(vc);
      *(u16x4*)&vt_lds[nb][srow][scol + 12] = hi4(vc);
      __syncthreads();
      cur = nb;
    }
  }

  auto epi = [&](f32x4 (&o)[2][4], float (&l_r)[2], const int q_lo) {
#pragma unroll
    for (int nf = 0; nf < 2; ++nf)
#pragma unroll
      for (int r = 0; r < 4; ++r) {
        const int qg = q_lo + nf * 16 + quad * 4 + r;
        const float inv = 1.0f / __shfl(l_r[nf], quad * 4 + r, 16);
        unsigned short* orow = Ow + rkbase + (size_t)qg * DM;
#pragma unroll
        for (int j = 0; j < 4; ++j)
          orow[j * 16 + c16] = f2bf(o[nf][j][r] * inv);
      }
  };
  epi(oA, lA, q_loA);
  epi(oB, lB, q_loB);
}

extern "C" void kernel_launch(void* const* d_in, const int* in_sizes, int n_in,
                              void* d_out, int out_size, void* d_ws, size_t ws_size,
                              hipStream_t stream) {
  const float* x_q  = (const float*)d_in[0];
  const float* x_kv = (const float*)d_in[1];
  const float* Wq   = (const float*)d_in[2];
  const float* Wk   = (const float*)d_in[3];
  const float* Wv   = (const float*)d_in[4];
  const float* Wo   = (const float*)d_in[5];
  float* out = (float*)d_out;

  // d_out (32MB) = Sx_kv | Sx_q (exact fit); fully overwritten by final GEMM.
  unsigned short* Sxkv = (unsigned short*)d_out;
  unsigned short* Sxq  = Sxkv + (size_t)MROWS * DM;

  // ws: qb | kb | vtb | Wk_b|Wv_b|Wq_b (contiguous 3072x1024) | Wo_b = 56MB.
  unsigned short* qb   = (unsigned short*)d_ws;
  unsigned short* kb   = qb + (size_t)MROWS * DM;
  unsigned short* vtb  = kb + (size_t)MROWS * DM;      // Vt[b][h][d][t]
  unsigned short* Wk_b = vtb + (size_t)MROWS * DM;
  unsigned short* Wo_b = Wk_b + (size_t)3 * DM * DM;

  const int nW8 = DM * DM / 8;
  const int nX8 = MROWS * DM / 8;

  // stage 1: 4 weights + x_kv + x_q in one dispatch
  conv_stage1<<<4 * (nW8 / 256) + 2 * (nX8 / 256), 256, 0, stream>>>(
      Wk, Wv, Wq, Wo, x_kv, x_q, Wk_b, Wo_b, Sxkv, Sxq);

  // Mega-QKV with counted-vmcnt 4-phase schedule: 384 blocks x 512 thr.
  gemm_qkv_p4<<<dim3(3 * DM / 256, MROWS / 256), 512, 0, stream>>>(
      Sxkv, Sxq, Wk_b, kb, vtb, qb, MROWS, 3 * DM, DM);
  attn_flash2<<<dim3(8, NH, BB), 256, 0, stream>>>(qb, kb, vtb, qb);
  gemm128<1><<<dim3(DM / 128, MROWS / 128), 256, 0, stream>>>(
      qb, Wo_b, out, MROWS, DM, DM);
}

// Round 13
// 294.165 us; speedup vs baseline: 1.0185x; 1.0185x over previous
//
#include <hip/hip_runtime.h>
#include <stdint.h>

#define T_SEQ 2048
#define NH 16
#define HD 64
#define DM 1024
#define BB 4
#define MROWS (BB * T_SEQ)   // 8192

// Q projection is pre-scaled by 1/sqrt(HD) * log2(e) so attention scores are
// already in the log2 domain: P = exp2(s - m), alpha = exp2(m_old - m_new).
#define QSCALE 0.18033688011112042f  // 0.125 * log2(e)

typedef __attribute__((ext_vector_type(8))) __bf16 bf16x8;
typedef __attribute__((ext_vector_type(8))) unsigned short u16x8;
typedef __attribute__((ext_vector_type(4))) unsigned short u16x4;
typedef __attribute__((ext_vector_type(4))) float f32x4;

// Native cast -> compiler emits v_cvt_pk_bf16_f32 (RNE, pairs fuse).
__device__ __forceinline__ unsigned short f2bf(float f) {
  return __builtin_bit_cast(unsigned short, (__bf16)f);
}

__device__ __forceinline__ bf16x8 ld8_f32(const float* __restrict__ p) {
  f32x4 a = *(const f32x4*)p;
  f32x4 b = *(const f32x4*)(p + 4);
  u16x8 u;
#pragma unroll
  for (int i = 0; i < 4; ++i) {
    u[i]     = f2bf(a[i]);
    u[i + 4] = f2bf(b[i]);
  }
  return __builtin_bit_cast(bf16x8, u);
}

__device__ __forceinline__ bf16x8 ld8_bf(const unsigned short* p) {
  return __builtin_bit_cast(bf16x8, *(const u16x8*)p);
}

// 8-aligned LDS read as two b64s (stride-68 layouts are not 16B-aligned)
__device__ __forceinline__ bf16x8 ld8_lds(const unsigned short* p) {
  u16x4 a = *(const u16x4*)p;
  u16x4 b = *(const u16x4*)(p + 4);
  return __builtin_bit_cast(bf16x8,
      __builtin_shufflevector(a, b, 0, 1, 2, 3, 4, 5, 6, 7));
}

__device__ __forceinline__ u16x4 lo4(u16x8 v) {
  return __builtin_shufflevector(v, v, 0, 1, 2, 3);
}
__device__ __forceinline__ u16x4 hi4(u16x8 v) {
  return __builtin_shufflevector(v, v, 4, 5, 6, 7);
}

__device__ __forceinline__ void gload_lds16(const unsigned short* g,
                                            unsigned short* l) {
  __builtin_amdgcn_global_load_lds(
      (const __attribute__((address_space(1))) unsigned int*)g,
      (__attribute__((address_space(3))) unsigned int*)l, 16, 0, 0);
}

// ---------------------------------------------------------------------------
// Fused stage-1 conversion — 4 weights + x_kv + x_q in ONE dispatch.
// ---------------------------------------------------------------------------
__global__ __launch_bounds__(256) void conv_stage1(
    const float* __restrict__ Wk, const float* __restrict__ Wv,
    const float* __restrict__ Wq, const float* __restrict__ Wo,
    const float* __restrict__ xkv, const float* __restrict__ xq,
    unsigned short* __restrict__ Wkb012, unsigned short* __restrict__ Wob,
    unsigned short* __restrict__ Sxkv, unsigned short* __restrict__ Sxq) {
  const int bid = blockIdx.x;
  const int WSEG = (DM * DM / 8) / 256;   // 512 blocks per weight
  const int XSEG = (MROWS * DM / 8) / 256;  // 4096 blocks per activation
  if (bid < 4 * WSEG) {
    const int w = bid >> 9;
    const float* src = (w == 0) ? Wk : (w == 1) ? Wv : (w == 2) ? Wq : Wo;
    unsigned short* dst = (w < 3) ? Wkb012 + (size_t)w * DM * DM : Wob;
    const int i = (bid & (WSEG - 1)) * 256 + threadIdx.x;
    *(u16x8*)(dst + (size_t)i * 8) =
        __builtin_bit_cast(u16x8, ld8_f32(src + (size_t)i * 8));
  } else if (bid < 4 * WSEG + XSEG) {
    const int i = (bid - 4 * WSEG) * 256 + threadIdx.x;
    *(u16x8*)(Sxkv + (size_t)i * 8) =
        __builtin_bit_cast(u16x8, ld8_f32(xkv + (size_t)i * 8));
  } else {
    const int i = (bid - 4 * WSEG - XSEG) * 256 + threadIdx.x;
    *(u16x8*)(Sxq + (size_t)i * 8) =
        __builtin_bit_cast(u16x8, ld8_f32(xq + (size_t)i * 8));
  }
}

// ---------------------------------------------------------------------------
// R12: counted-vmcnt pipelined GEMM, PERFECT-ROUND grids (every dispatch =
// 256 blocks = 1 block/CU, no half-empty scheduling round — R11's 384-block
// grid ran 256+128 and wasted half the machine for half the time).
// C = A[M,K] @ B[N,K]^T, BM=256, BN=256 or 128, BK=64, 512 thr (8 waves).
//   BN=256: waves 2Mx4N, wave out 128x64, acc[8][4]; 8 stage calls/K-tile,
//           vmcnt(8); LDS 128KB. (verbatim R11 pipeline — refcheck'd)
//   BN=128: waves 4Mx2N, wave out 64x64, acc[4][4]; 6 stage calls/K-tile,
//           vmcnt(6); LDS 96KB.
// Pipeline per K-tile kt (buf cur=kt&1): B-frags once; PH phases x
//   {A-frag ds_reads, setprio(1), 16 MFMA, setprio(0), raw barrier};
//   boundary: lgkmcnt(0); barrier; stage tile kt+2 -> buf cur;
//   vmcnt(CALLS) (tile kt+1's loads -- one full K-tile in flight -- landed;
//   kt+2's stay outstanding, never drains to 0 in steady state).
// LDS XOR slot-swizzle both-sides (src col pre-swizzled so linear gload_lds
// dest lands swizzled; ds_read applies same XOR). Bank-conflict = 0 (R11).
// MODE 3: KV split epilogue (n0<DM -> K row-major; else Vt[b][h][d][t]).
// MODE 4: bf16 row-major * QSCALE (Q). MODE 1: f32 row-major (O).
// ---------------------------------------------------------------------------
template <int BN, int MODE>
__global__ __launch_bounds__(512, 2) void gemm_p4(
    const unsigned short* __restrict__ A, const unsigned short* __restrict__ B,
    void* __restrict__ C1, void* __restrict__ C2, int M, int N, int K) {
  constexpr int BM = 256;
  constexpr int BHALF = BN / 128;           // 2 or 1
  constexpr int WM = (BN == 256) ? 2 : 4;   // waves tiling M
  constexpr int RM = (BM / WM) / 16;        // 8 or 4
  constexpr int PH = RM / 2;                // 4 or 2 phases

  __shared__ __align__(16) unsigned short As[2][2][128 * 64];
  __shared__ __align__(16) unsigned short Bs[2][BHALF][128 * 64];

  const int t = threadIdx.x;               // 0..511
  const int lane = t & 63, wave = t >> 6;  // 8 waves
  const int lin = (int)(blockIdx.x + gridDim.x * blockIdx.y);  // 0..255
  const int nx = N / BN;
  const int mpx = (M >> 8) >> 3;           // m-panels per XCD
  const int xcd = lin & 7, slot = lin >> 3;
  const int m0 = (xcd * mpx + slot / nx) * BM;
  const int n0 = (slot % nx) * BN;

  // staging: thread t -> row tr (0..63), pre-swizzled source col tc, so the
  // linear gload_lds dest lands slot-swizzled (phys slot (t&7)^(tr&7)).
  const int tr = t >> 3;
  const int tc = ((t & 7) ^ (tr & 7)) * 8;
  const unsigned short* ga = A + (size_t)(m0 + tr) * K + tc;
  const unsigned short* gb = B + (size_t)(n0 + tr) * K + tc;
  const int ldst = wave * 512;             // u16; one call = 64 rows x 64 col

  const int wm = (BN == 256) ? (wave >> 2) : (wave >> 1);
  const int wn = (BN == 256) ? (wave & 3) : (wave & 1);
  const int fr = lane & 15, quad = lane >> 4;
  const int sw = fr & 7;

  f32x4 acc[RM][4];
#pragma unroll
  for (int i = 0; i < RM; ++i)
#pragma unroll
    for (int j = 0; j < 4; ++j) acc[i][j] = (f32x4){0.f, 0.f, 0.f, 0.f};

  auto stage_tile = [&](int b, int k0) {  // 4 + 2*BHALF gload_lds per thread
#pragma unroll
    for (int h = 0; h < 4; ++h)
      gload_lds16(ga + (size_t)(h * 64) * K + k0,
                  &As[b][h >> 1][(h & 1) * 4096 + ldst]);
#pragma unroll
    for (int h = 0; h < 2 * BHALF; ++h)
      gload_lds16(gb + (size_t)(h * 64) * K + k0,
                  &Bs[b][h >> 1][(h & 1) * 4096 + ldst]);
  };

  stage_tile(0, 0);
  stage_tile(1, 64);
  if constexpr (BN == 256)
    asm volatile("s_waitcnt vmcnt(8)" ::: "memory");
  else
    asm volatile("s_waitcnt vmcnt(6)" ::: "memory");
  __builtin_amdgcn_s_barrier();

  const int NT = K >> 6;  // 16
  for (int kt = 0; kt < NT; ++kt) {
    const int cur = kt & 1;
    // B-frags for the whole K-tile, live across phases.
    bf16x8 bfr[2][4];
    const int bh = (BN == 256) ? (wn >> 1) : 0;
    const int brb = (BN == 256) ? (wn & 1) * 64 : wn * 64;
#pragma unroll
    for (int ks = 0; ks < 2; ++ks)
#pragma unroll
      for (int j = 0; j < 4; ++j) {
        const int br = brb + j * 16 + fr;            // br&7 == fr&7
        bfr[ks][j] =
            ld8_bf(&Bs[cur][bh][br * 64 + ((ks * 4 + quad) ^ sw) * 8]);
      }
#pragma unroll
    for (int p = 0; p < PH; ++p) {
      bf16x8 af[2][2];  // [di][ks]
#pragma unroll
      for (int di = 0; di < 2; ++di)
#pragma unroll
        for (int ks = 0; ks < 2; ++ks) {
          const int ar = wm * (BM / WM) + (p * 2 + di) * 16 + fr;  // 0..255
          af[di][ks] = ld8_bf(
              &As[cur][ar >> 7][(ar & 127) * 64 + ((ks * 4 + quad) ^ sw) * 8]);
        }
      __builtin_amdgcn_s_setprio(1);
#pragma unroll
      for (int di = 0; di < 2; ++di)
#pragma unroll
        for (int j = 0; j < 4; ++j)
#pragma unroll
          for (int ks = 0; ks < 2; ++ks)
            acc[p * 2 + di][j] = __builtin_amdgcn_mfma_f32_16x16x32_bf16(
                af[di][ks], bfr[ks][j], acc[p * 2 + di][j], 0, 0, 0);
      __builtin_amdgcn_s_setprio(0);
      if (p < PH - 1) __builtin_amdgcn_s_barrier();  // phase alignment
    }
    // ---- K-tile boundary ----
    asm volatile("s_waitcnt lgkmcnt(0)" ::: "memory");  // my reads retired
    __builtin_amdgcn_s_barrier();   // all waves done reading buf cur
    if (kt + 2 < NT) {
      stage_tile(cur, (kt + 2) << 6);                   // overwrite buf cur
      if constexpr (BN == 256)
        asm volatile("s_waitcnt vmcnt(8)" ::: "memory");  // kt+1 landed
      else
        asm volatile("s_waitcnt vmcnt(6)" ::: "memory");
    } else {
      asm volatile("s_waitcnt vmcnt(0)" ::: "memory");  // tail drain
    }
    __builtin_amdgcn_s_barrier();   // tile kt+1 visible to all waves
  }

  // ---- epilogue ----
  const int orow = (lane >> 4) * 4, ocol = lane & 15;
  const int mwo = wm * (BM / WM), nwo = wn * 64;
#pragma unroll
  for (int i = 0; i < RM; ++i)
#pragma unroll
    for (int j = 0; j < 4; ++j) {
      const int mb = m0 + mwo + i * 16 + orow;
      const int n = n0 + nwo + j * 16 + ocol;
      if constexpr (MODE == 3) {
        if (n0 < DM) {            // K: bf16 row-major, stride DM
#pragma unroll
          for (int r = 0; r < 4; ++r)
            ((unsigned short*)C1)[(size_t)(mb + r) * DM + n] =
                f2bf(acc[i][j][r]);
        } else {                  // V: Vt[b][h][d][t], 4 r = consecutive t
          const int nv = n - DM;
          u16x4 pk;
#pragma unroll
          for (int r = 0; r < 4; ++r) pk[r] = f2bf(acc[i][j][r]);
          unsigned short* dst = (unsigned short*)C2 +
              ((size_t)((mb >> 11) * NH + (nv >> 6)) * HD + (nv & 63)) *
                  T_SEQ +
              (mb & 2047);
          *(u16x4*)dst = pk;
        }
      } else if constexpr (MODE == 4) {  // Q: bf16 row-major * QSCALE
#pragma unroll
        for (int r = 0; r < 4; ++r)
          ((unsigned short*)C1)[(size_t)(mb + r) * N + n] =
              f2bf(acc[i][j][r] * QSCALE);
      } else {                    // MODE 1: f32 row-major
#pragma unroll
        for (int r = 0; r < 4; ++r)
          ((float*)C1)[(size_t)(mb + r) * N + n] = acc[i][j][r];
      }
    }
}

// ---------------------------------------------------------------------------
// MFMA flash attention v2 (causal) — R7 version (best measured 88-91 µs).
// Paired q-tiles {15-pi, pi}; S^T = K @ Q^T; scores pre-scaled to log2
// domain; defer-max THR=8; alpha/l via width-16 shuffles; K/V LDS
// double-buffer, 1 barrier/tile.
// ---------------------------------------------------------------------------
#define ASTR 68

__global__ __launch_bounds__(256, 2) void attn_flash2(
    const unsigned short* Qw, const unsigned short* __restrict__ Kw,
    const unsigned short* __restrict__ Vt, unsigned short* Ow) {
  __shared__ __align__(16) unsigned short k_lds[2][64][ASTR];
  __shared__ __align__(16) unsigned short vt_lds[2][64][ASTR];
  __shared__ __align__(16) unsigned short p_lds[4][32][ASTR];

  const int tid = threadIdx.x, lane = tid & 63, wave = tid >> 6;
  const int c16 = lane & 15, quad = lane >> 4;
  const int b = blockIdx.z, h = blockIdx.y;
  const int pi = blockIdx.x;            // pair index 0..7
  const int qb0A = (15 - pi) * 128;     // heavy
  const int qb0B = pi * 128;            // light
  const size_t rkbase = (size_t)b * T_SEQ * DM + (size_t)h * HD;
  const size_t vtbase = (size_t)(b * NH + h) * HD * T_SEQ;

  const int q_loA = qb0A + wave * 32;
  const int q_loB = qb0B + wave * 32;

  bf16x8 qfA[2][2], qfB[2][2];
#pragma unroll
  for (int nf = 0; nf < 2; ++nf) {
    const unsigned short* qpA =
        Qw + rkbase + (size_t)(q_loA + nf * 16 + c16) * DM + quad * 8;
    qfA[nf][0] = ld8_bf(qpA);
    qfA[nf][1] = ld8_bf(qpA + 32);
    const unsigned short* qpB =
        Qw + rkbase + (size_t)(q_loB + nf * 16 + c16) * DM + quad * 8;
    qfB[nf][0] = ld8_bf(qpB);
    qfB[nf][1] = ld8_bf(qpB + 32);
  }

  f32x4 oA[2][4], oB[2][4];
#pragma unroll
  for (int nf = 0; nf < 2; ++nf)
#pragma unroll
    for (int j = 0; j < 4; ++j) {
      oA[nf][j] = (f32x4){0.f, 0.f, 0.f, 0.f};
      oB[nf][j] = (f32x4){0.f, 0.f, 0.f, 0.f};
    }
  float mA[2] = {-3.0e38f, -3.0e38f}, lA[2] = {0.f, 0.f};
  float mB[2] = {-3.0e38f, -3.0e38f}, lB[2] = {0.f, 0.f};

  const int srow = tid >> 2;
  const int scol = (tid & 3) * 16;
  const int ntiles = (qb0A + 191) >> 6;
  const int ntA_w = (q_loA + 95) >> 6;
  const int ntB_w = (q_loB + 95) >> 6;

  const unsigned short* kp0 = Kw + rkbase + (size_t)srow * DM + scol;
  const unsigned short* vp0 = Vt + vtbase + (size_t)srow * T_SEQ + scol;

  auto subtile = [&](const bf16x8 (&qf)[2][2], f32x4 (&o)[2][4],
                     float (&m_r)[2], float (&l_r)[2], const int q_lo,
                     const int kb0, const int bi) {
    f32x4 s[4][2];
    __builtin_amdgcn_s_setprio(1);
#pragma unroll
    for (int mf = 0; mf < 4; ++mf) {
      const unsigned short* kr = &k_lds[bi][mf * 16 + c16][quad * 8];
      const bf16x8 k0 = ld8_lds(kr);
      const bf16x8 k1 = ld8_lds(kr + 32);
#pragma unroll
      for (int nf = 0; nf < 2; ++nf) {
        f32x4 a = {0.f, 0.f, 0.f, 0.f};
        a = __builtin_amdgcn_mfma_f32_16x16x32_bf16(k0, qf[nf][0], a, 0, 0, 0);
        a = __builtin_amdgcn_mfma_f32_16x16x32_bf16(k1, qf[nf][1], a, 0, 0, 0);
        s[mf][nf] = a;
      }
    }
    __builtin_amdgcn_s_setprio(0);
    if (kb0 + 63 > q_lo) {
#pragma unroll
      for (int mf = 0; mf < 4; ++mf) {
        const int key0 = kb0 + mf * 16 + quad * 4;
#pragma unroll
        for (int nf = 0; nf < 2; ++nf) {
          const int qg = q_lo + nf * 16 + c16;
#pragma unroll
          for (int r = 0; r < 4; ++r)
            if (key0 + r > qg) s[mf][nf][r] = -3.0e38f;
        }
      }
    }

#pragma unroll
    for (int nf = 0; nf < 2; ++nf) {
      float mx = -3.0e38f;
#pragma unroll
      for (int mf = 0; mf < 4; ++mf)
#pragma unroll
        for (int r = 0; r < 4; ++r) mx = fmaxf(mx, s[mf][nf][r]);
      mx = fmaxf(mx, __shfl_xor(mx, 16, 64));
      mx = fmaxf(mx, __shfl_xor(mx, 32, 64));
      if (!__all(mx - m_r[nf] <= 8.0f)) {
        const float m_new = fmaxf(m_r[nf], mx);
        const float al = exp2f(m_r[nf] - m_new);
        m_r[nf] = m_new;
        l_r[nf] *= al;
        float alr[4];
#pragma unroll
        for (int r = 0; r < 4; ++r) alr[r] = __shfl(al, quad * 4 + r, 16);
#pragma unroll
        for (int j = 0; j < 4; ++j)
#pragma unroll
          for (int r = 0; r < 4; ++r) o[nf][j][r] *= alr[r];
      }
      float ps = 0.f;
#pragma unroll
      for (int mf = 0; mf < 4; ++mf) {
        u16x4 pk;
#pragma unroll
        for (int r = 0; r < 4; ++r) {
          const float e = exp2f(s[mf][nf][r] - m_r[nf]);
          ps += e;
          pk[r] = f2bf(e);
        }
        *(u16x4*)&p_lds[wave][nf * 16 + c16][mf * 16 + quad * 4] = pk;
      }
      ps += __shfl_xor(ps, 16, 64);
      ps += __shfl_xor(ps, 32, 64);
      l_r[nf] += ps;
    }
    __threadfence_block();

    bf16x8 pf[2][2];
#pragma unroll
    for (int nf = 0; nf < 2; ++nf) {
      const unsigned short* pw = &p_lds[wave][nf * 16 + c16][quad * 8];
      pf[nf][0] = ld8_lds(pw);
      pf[nf][1] = ld8_lds(pw + 32);
    }
    __builtin_amdgcn_s_setprio(1);
#pragma unroll
    for (int j = 0; j < 4; ++j) {
      const unsigned short* vr = &vt_lds[bi][j * 16 + c16][quad * 8];
      const bf16x8 v0 = ld8_lds(vr);
      const bf16x8 v1 = ld8_lds(vr + 32);
#pragma unroll
      for (int nf = 0; nf < 2; ++nf) {
        o[nf][j] = __builtin_amdgcn_mfma_f32_16x16x32_bf16(pf[nf][0], v0,
                                                           o[nf][j], 0, 0, 0);
        o[nf][j] = __builtin_amdgcn_mfma_f32_16x16x32_bf16(pf[nf][1], v1,
                                                           o[nf][j], 0, 0, 0);
      }
    }
    __builtin_amdgcn_s_setprio(0);
  };

  {
    u16x8 ka = *(const u16x8*)kp0;
    u16x8 kc = *(const u16x8*)(kp0 + 8);
    u16x8 va = *(const u16x8*)vp0;
    u16x8 vc = *(const u16x8*)(vp0 + 8);
    *(u16x4*)&k_lds[0][srow][scol]       = lo4(ka);
    *(u16x4*)&k_lds[0][srow][scol + 4]   = hi4(ka);
    *(u16x4*)&k_lds[0][srow][scol + 8]   = lo4(kc);
    *(u16x4*)&k_lds[0][srow][scol + 12]  = hi4(kc);
    *(u16x4*)&vt_lds[0][srow][scol]      = lo4(va);
    *(u16x4*)&vt_lds[0][srow][scol + 4]  = hi4(va);
    *(u16x4*)&vt_lds[0][srow][scol + 8]  = lo4(vc);
    *(u16x4*)&vt_lds[0][srow][scol + 12] = hi4(vc);
  }
  __syncthreads();

  int cur = 0;
  for (int t = 0; t < ntiles; ++t) {
    const int kb0 = t * 64;
    const bool pf = (t + 1 < ntiles);
    u16x8 ka, kc, va, vc;
    if (pf) {
      const unsigned short* kp = kp0 + (size_t)(kb0 + 64) * DM;
      ka = *(const u16x8*)kp;
      kc = *(const u16x8*)(kp + 8);
      const unsigned short* vp = vp0 + (kb0 + 64);
      va = *(const u16x8*)vp;
      vc = *(const u16x8*)(vp + 8);
    }
    if (t < ntA_w) subtile(qfA, oA, mA, lA, q_loA, kb0, cur);
    if (t < ntB_w) subtile(qfB, oB, mB, lB, q_loB, kb0, cur);
    if (pf) {
      const int nb = cur ^ 1;
      *(u16x4*)&k_lds[nb][srow][scol]       = lo4(ka);
      *(u16x4*)&k_lds[nb][srow][scol + 4]   = hi4(ka);
      *(u16x4*)&k_lds[nb][srow][scol + 8]   = lo4(kc);
      *(u16x4*)&k_lds[nb][srow][scol + 12]  = hi4(kc);
      *(u16x4*)&vt_lds[nb][srow][scol]      = lo4(va);
      *(u16x4*)&vt_lds[nb][srow][scol + 4]  = hi4(va);
      *(u16x4*)&vt_lds[nb][srow][scol + 8]  = lo4(vc);
      *(u16x4*)&vt_lds[nb][srow][scol + 12] = hi4(vc);
      __syncthreads();
      cur = nb;
    }
  }

  auto epi = [&](f32x4 (&o)[2][4], float (&l_r)[2], const int q_lo) {
#pragma unroll
    for (int nf = 0; nf < 2; ++nf)
#pragma unroll
      for (int r = 0; r < 4; ++r) {
        const int qg = q_lo + nf * 16 + quad * 4 + r;
        const float inv = 1.0f / __shfl(l_r[nf], quad * 4 + r, 16);
        unsigned short* orow = Ow + rkbase + (size_t)qg * DM;
#pragma unroll
        for (int j = 0; j < 4; ++j)
          orow[j * 16 + c16] = f2bf(o[nf][j][r] * inv);
      }
  };
  epi(oA, lA, q_loA);
  epi(oB, lB, q_loB);
}

extern "C" void kernel_launch(void* const* d_in, const int* in_sizes, int n_in,
                              void* d_out, int out_size, void* d_ws, size_t ws_size,
                              hipStream_t stream) {
  const float* x_q  = (const float*)d_in[0];
  const float* x_kv = (const float*)d_in[1];
  const float* Wq   = (const float*)d_in[2];
  const float* Wk   = (const float*)d_in[3];
  const float* Wv   = (const float*)d_in[4];
  const float* Wo   = (const float*)d_in[5];
  float* out = (float*)d_out;

  // d_out (32MB) = Sx_kv | Sx_q (exact fit); fully overwritten by final GEMM.
  unsigned short* Sxkv = (unsigned short*)d_out;
  unsigned short* Sxq  = Sxkv + (size_t)MROWS * DM;

  // ws: qb | kb | vtb | Wk_b|Wv_b|Wq_b (contiguous 3072x1024) | Wo_b = 56MB.
  unsigned short* qb   = (unsigned short*)d_ws;
  unsigned short* kb   = qb + (size_t)MROWS * DM;
  unsigned short* vtb  = kb + (size_t)MROWS * DM;      // Vt[b][h][d][t]
  unsigned short* Wk_b = vtb + (size_t)MROWS * DM;
  unsigned short* Wq_b = Wk_b + (size_t)2 * DM * DM;
  unsigned short* Wo_b = Wk_b + (size_t)3 * DM * DM;

  const int nW8 = DM * DM / 8;
  const int nX8 = MROWS * DM / 8;

  // stage 1: 4 weights + x_kv + x_q in one dispatch
  conv_stage1<<<4 * (nW8 / 256) + 2 * (nX8 / 256), 256, 0, stream>>>(
      Wk, Wv, Wq, Wo, x_kv, x_q, Wk_b, Wo_b, Sxkv, Sxq);

  // KV: p4 256x256, N=2048 over [Wk|Wv] -> 256 blocks = 1 full round.
  gemm_p4<256, 3><<<dim3(2 * DM / 256, MROWS / 256), 512, 0, stream>>>(
      Sxkv, Wk_b, kb, vtb, MROWS, 2 * DM, DM);
  // Q: p4 256x128, N=1024 -> 256 blocks = 1 full round (QSCALE folded).
  gemm_p4<128, 4><<<dim3(DM / 128, MROWS / 256), 512, 0, stream>>>(
      Sxq, Wq_b, qb, nullptr, MROWS, DM, DM);
  attn_flash2<<<dim3(8, NH, BB), 256, 0, stream>>>(qb, kb, vtb, qb);
  // O: p4 256x128, f32 out -> 256 blocks = 1 full round.
  gemm_p4<128, 1><<<dim3(DM / 128, MROWS / 256), 512, 0, stream>>>(
      qb, Wo_b, out, nullptr, MROWS, DM, DM);
}